// Round 6
// baseline (346.373 us; speedup 1.0000x reference)
//
#include <hip/hip_runtime.h>
#include <hip/hip_bf16.h>

typedef unsigned char uchar_t;
typedef __attribute__((ext_vector_type(4)))  float f32x4;
typedef __attribute__((ext_vector_type(16))) float f32x16;

#define B_SZ 8192
#define D_FT 784
#define N_KT 13
#define PLANE_U32 131072   // 8192 rows * 16 uints (64 B) per plane
#define PLANE_B   524288   // plane stride in bytes
#define THRESH 0.9f

#define GLOBAL_AS(p) ((const __attribute__((address_space(1))) void*)(p))
#define LDS_AS(p)    ((__attribute__((address_space(3))) void*)(p))

// Wave-per-row preproc: 2048 blocks x 4 waves; wave w handles row blockIdx*4+w.
// conv 2x2/s2 + bias -> 4x4 unitary -> qf (LDS, fp32), row norm -> qn fp8 e4m3.
// qn is K-PLANE-BLOCKED: qn[kt][row][64 B] (13 planes of 512 KB) so gram's
// per-kt staging reads are fully contiguous.
__global__ __launch_bounds__(256) void preproc_kernel(
    const float* __restrict__ x, const float* __restrict__ conv_w,
    const float* __restrict__ conv_b, const float* __restrict__ unitary,
    const float* __restrict__ lin_w, const float* __restrict__ lin_b,
    float* __restrict__ log_probs, uchar_t* __restrict__ qn)
{
    __shared__ float xr[4][784];
    __shared__ float qf[4][784];

    const int t = threadIdx.x, lane = t & 63, wave = t >> 6;
    const int b = blockIdx.x * 4 + wave;
    float* xw = xr[wave];
    float* qw = qf[wave];

    const float4* xsrc = (const float4*)(x + (size_t)b * 784);
    #pragma unroll
    for (int i = lane; i < 196; i += 64) ((float4*)xw)[i] = xsrc[i];
    __syncthreads();

    float sumsq = 0.f;
    for (int g = lane; g < 196; g += 64) {
        const int c = g / 49, p = g % 49;
        const float w00 = conv_w[c*4+0], w01 = conv_w[c*4+1];
        const float w10 = conv_w[c*4+2], w11 = conv_w[c*4+3];
        const float bcv = conv_b[c];
        float feat[4];
        #pragma unroll
        for (int j = 0; j < 4; ++j) {
            const int s = 4*p + j;
            const int h = s / 14, wq = s % 14;
            const float* px = &xw[(2*h)*28 + 2*wq];
            feat[j] = bcv + w00*px[0] + w01*px[1] + w10*px[28] + w11*px[29];
        }
        #pragma unroll
        for (int w = 0; w < 4; ++w) {
            float v = unitary[w*4+0]*feat[0] + unitary[w*4+1]*feat[1]
                    + unitary[w*4+2]*feat[2] + unitary[w*4+3]*feat[3];
            qw[4*g + w] = v;
            sumsq += v * v;
        }
    }
    __syncthreads();

    #pragma unroll
    for (int off = 1; off < 64; off <<= 1) sumsq += __shfl_xor(sumsq, off, 64);
    const float inv = 1.0f / (sqrtf(sumsq) + 1e-12f);

    // qn write, plane-blocked: uint i of this row -> plane i>>4, word i&15.
    unsigned int* qbase = (unsigned int*)qn;
    for (int i = lane; i < 208; i += 64) {
        unsigned int o = 0u;
        if (i < 196) {
            const float v0 = qw[4*i+0] * inv, v1 = qw[4*i+1] * inv;
            const float v2 = qw[4*i+2] * inv, v3 = qw[4*i+3] * inv;
            int lo = __builtin_amdgcn_cvt_pk_fp8_f32(v0, v1, 0, 0);
            o = (unsigned int)__builtin_amdgcn_cvt_pk_fp8_f32(v2, v3, lo, 1);
        }
        qbase[(size_t)(i >> 4) * PLANE_U32 + (size_t)b * 16 + (i & 15)] = o;
    }

    float acc[10];
    #pragma unroll
    for (int cl = 0; cl < 10; ++cl) acc[cl] = 0.f;
    for (int k = lane; k < 784; k += 64) {
        const float v = qw[k];
        #pragma unroll
        for (int cl = 0; cl < 10; ++cl) acc[cl] += v * lin_w[cl*784 + k];
    }
    #pragma unroll
    for (int cl = 0; cl < 10; ++cl) {
        #pragma unroll
        for (int off = 1; off < 64; off <<= 1)
            acc[cl] += __shfl_xor(acc[cl], off, 64);
        acc[cl] += lin_b[cl];
    }
    if (lane == 0) {
        float mx = -1e30f;
        #pragma unroll
        for (int cl = 0; cl < 10; ++cl) mx = fmaxf(mx, acc[cl]);
        float se = 0.f;
        #pragma unroll
        for (int cl = 0; cl < 10; ++cl) se += expf(acc[cl] - mx);
        const float lse = mx + logf(se);
        #pragma unroll
        for (int cl = 0; cl < 10; ++cl)
            log_probs[(size_t)b*10 + cl] = acc[cl] - lse;
    }
}

// R11 (= R10 resubmit + kt=12 vmcnt fix): 256x256-tile fp8 Gram, 8 waves
// (4x2 of 64x128), mfma_32x32x16_fp8_fp8, TRIPLE-buffered LDS (96 KB static),
// prefetch depth 2, ONE s_barrier per kt, per-kt counted vmcnt. 1 block/CU:
// latency hiding from the 2-deep pipeline, not lockstep-broken TLP (R0-R4:
// the 4-block 128^2 structure was insensitive to every knob). 528 blocks
// (= 8 x 66, XCD-bijective), half the staging traffic of 128^2.
//
// Per kt per wave: 4 glds (1 KB each) + 5 NT zero-stores + 24 ds_read_b64 +
// 32 mfma_32x32x16. Per-kt issue order: [STAGE kt+2: 4][zst kt: 5].
// FIFO vmcnt retire => at top of body kt the outstanding queue (young->old):
//   kt=0:        [S1 4][S0 4]                  -> vmcnt(4)
//   kt=1:        [zst0 5][S2 4][S1 4]          -> vmcnt(9)
//   kt in 2..11: [zst(kt-1) 5][S(kt+1) 4][zst(kt-2) 5][S(kt) 4] -> vmcnt(14)
//   kt=12:       [zst11 5][zst10 5][S12 4]     -> vmcnt(10)
// Buffer safety (3 buf, 1 barrier/kt): STAGE(kt+2) writes buf (kt+2)%3 =
// (kt-1)%3, whose ds_reads completed before each wave reached barrier(kt).
//
// LDS per 16-row block rb (1 KB): [chunk 0..3][row 0..15][16 B]; glds lane map
// row=lane&15, chunk=lane>>4 matches dest base+lane*16 (linear, plane-blocked
// source is 16 rows x 64 B contiguous). Fragment (32x32x16): lane l, kstep s:
// byte-in-row = s*16 + (l>>5)*8 -> addr rb*1024 + s*256 + (r&15)*16 + (l>>5)*8.
// C/D: col = lane&31, row = (reg&3) + 8*(reg>>2) + 4*(lane>>5).
__global__ __launch_bounds__(512, 2) void gram_kernel(
    const uchar_t* __restrict__ qn, float* __restrict__ adj)
{
    // XCD-bijective swizzle: 528 = 8 * 66.
    const int t0 = blockIdx.x;
    int tl = (t0 & 7) * 66 + (t0 >> 3);
    // triangular decode (32 tile-rows): cum(r) = r*(65-r)/2
    int br = (int)((65.0 - sqrt(4225.0 - 8.0 * (double)tl)) * 0.5);
    while ((br + 1) * (65 - (br + 1)) / 2 <= tl) ++br;
    while (br * (65 - br) / 2 > tl) --br;
    const int bc = br + (tl - br * (65 - br) / 2);

    __shared__ uchar_t ldsA[3][16384] __attribute__((aligned(16)));  // 48 KB
    __shared__ uchar_t ldsB[3][16384] __attribute__((aligned(16)));  // 48 KB

    const int t = threadIdx.x;
    const int lane = t & 63, wave = t >> 6;       // 8 waves
    const int wrow = wave >> 1, wcol = wave & 1;  // 4x2 -> 64x128 per wave
    const int l32 = lane & 31, half = lane >> 5;

    const bool offdiag = (br != bc);
    const int br256 = br * 256, bc256 = bc * 256;
    // zero-injection: offdiag owns 2 mirror 256^2 tiles (32768 f32x4), diag 1
    // (16384). 5 stores/thread/kt, pow2 mask -> wave-invariant vmcnt counts.
    const int zmask = offdiag ? 32767 : 16383;

    // staging: wave w stages A rowblocks {w, w+8} and B rowblocks {w, w+8}.
    const int srow = lane & 15, sck = (lane >> 4) * 16;
    const uchar_t* gA0 = qn + (size_t)(br256 + wave*16       + srow) * 64 + sck;
    const uchar_t* gA1 = qn + (size_t)(br256 + (wave+8)*16   + srow) * 64 + sck;
    const uchar_t* gB0 = qn + (size_t)(bc256 + wave*16       + srow) * 64 + sck;
    const uchar_t* gB1 = qn + (size_t)(bc256 + (wave+8)*16   + srow) * 64 + sck;
    const int ld0 = wave * 1024, ld1 = (wave + 8) * 1024;

    #define STAGE(p, koff) do {                                                            \
        __builtin_amdgcn_global_load_lds(GLOBAL_AS(gA0 + (koff)), LDS_AS(&ldsA[p][ld0]), 16, 0, 0); \
        __builtin_amdgcn_global_load_lds(GLOBAL_AS(gA1 + (koff)), LDS_AS(&ldsA[p][ld1]), 16, 0, 0); \
        __builtin_amdgcn_global_load_lds(GLOBAL_AS(gB0 + (koff)), LDS_AS(&ldsB[p][ld0]), 16, 0, 0); \
        __builtin_amdgcn_global_load_lds(GLOBAL_AS(gB1 + (koff)), LDS_AS(&ldsB[p][ld1]), 16, 0, 0); \
    } while (0)

    // fragment LDS byte offsets (without kstep term): r_local -> block layout
    int aoff[2], boff[4];
    #pragma unroll
    for (int mi = 0; mi < 2; ++mi) {
        const int r = wrow*64 + mi*32 + l32;
        aoff[mi] = (r >> 4)*1024 + (r & 15)*16 + half*8;
    }
    #pragma unroll
    for (int ni = 0; ni < 4; ++ni) {
        const int c = wcol*128 + ni*32 + l32;
        boff[ni] = (c >> 4)*1024 + (c & 15)*16 + half*8;
    }

    f32x16 acc[2][4] = {};
    STAGE(0, 0);
    STAGE(1, PLANE_B);

    #pragma unroll
    for (int kt = 0; kt < N_KT; ++kt) {
        const int p = kt % 3, p2 = (kt + 2) % 3;

        asm volatile("" ::: "memory");
        if (kt == 0)               __builtin_amdgcn_s_waitcnt(0xF74); // vmcnt(4)
        else if (kt == 1)          __builtin_amdgcn_s_waitcnt(0xF79); // vmcnt(9)
        else if (kt == N_KT - 1)   __builtin_amdgcn_s_waitcnt(0xF7A); // vmcnt(10)
        else                       __builtin_amdgcn_s_waitcnt(0xF7E); // vmcnt(14)
        __builtin_amdgcn_s_barrier();            // tile kt in LDS; buf kt-1 dead
        asm volatile("" ::: "memory");

        if (kt + 2 < N_KT) STAGE(p2, (size_t)(kt + 2) * PLANE_B);
        asm volatile("" ::: "memory");

        // zero-injection: exactly 5 coalesced NT f32x4 stores per thread,
        // issued AFTER the glds (FIFO vmcnt counting relies on this order).
        {
            f32x4 z = {0.f, 0.f, 0.f, 0.f};
            #pragma unroll
            for (int j = 0; j < 5; ++j) {
                const int idx  = (kt * 2560 + j * 512 + t) & zmask;
                const int tile = idx >> 14;            // always 0 for diag
                const int r    = (idx >> 6) & 255;
                const int c4   = idx & 63;
                const int rowb = tile ? bc256 : br256;
                const int colb = tile ? br256 : bc256;
                __builtin_nontemporal_store(
                    z, (f32x4*)adj + (size_t)(rowb + r) * 2048 + (colb >> 2) + c4);
            }
        }
        asm volatile("" ::: "memory");

        #pragma unroll
        for (int s = 0; s < 4; ++s) {
            long a0 = *(const long*)&ldsA[p][aoff[0] + s*256];
            long a1 = *(const long*)&ldsA[p][aoff[1] + s*256];
            long b0 = *(const long*)&ldsB[p][boff[0] + s*256];
            long b1 = *(const long*)&ldsB[p][boff[1] + s*256];
            long b2 = *(const long*)&ldsB[p][boff[2] + s*256];
            long b3 = *(const long*)&ldsB[p][boff[3] + s*256];
            acc[0][0] = __builtin_amdgcn_mfma_f32_32x32x16_fp8_fp8(a0, b0, acc[0][0], 0, 0, 0);
            acc[1][0] = __builtin_amdgcn_mfma_f32_32x32x16_fp8_fp8(a1, b0, acc[1][0], 0, 0, 0);
            acc[0][1] = __builtin_amdgcn_mfma_f32_32x32x16_fp8_fp8(a0, b1, acc[0][1], 0, 0, 0);
            acc[1][1] = __builtin_amdgcn_mfma_f32_32x32x16_fp8_fp8(a1, b1, acc[1][1], 0, 0, 0);
            acc[0][2] = __builtin_amdgcn_mfma_f32_32x32x16_fp8_fp8(a0, b2, acc[0][2], 0, 0, 0);
            acc[1][2] = __builtin_amdgcn_mfma_f32_32x32x16_fp8_fp8(a1, b2, acc[1][2], 0, 0, 0);
            acc[0][3] = __builtin_amdgcn_mfma_f32_32x32x16_fp8_fp8(a0, b3, acc[0][3], 0, 0, 0);
            acc[1][3] = __builtin_amdgcn_mfma_f32_32x32x16_fp8_fp8(a1, b3, acc[1][3], 0, 0, 0);
        }
    }
    #undef STAGE

    // Order all zero stores (block-wide) before the sparse 1-fixups.
    asm volatile("" ::: "memory");
    __builtin_amdgcn_s_waitcnt(0xF70);   // vmcnt(0): this wave's zeros done
    __builtin_amdgcn_s_barrier();        // all waves' zeros done
    asm volatile("" ::: "memory");

    // Sparse epilogue: fid = c^2, threshold, zero diagonal. Zeros already
    // written; only store reg-quads containing a 1 (__any guard).
    #pragma unroll
    for (int mi = 0; mi < 2; ++mi) {
        const int rbase = br256 + wrow*64 + mi*32 + 4*half;
        #pragma unroll
        for (int ni = 0; ni < 4; ++ni) {
            const int gc = bc256 + wcol*128 + ni*32 + l32;
            const f32x16 v = acc[mi][ni];
            #pragma unroll
            for (int q = 0; q < 4; ++q) {
                const int gr0 = rbase + 8*q;
                float o[4];
                bool h = false;
                #pragma unroll
                for (int r = 0; r < 4; ++r) {
                    const float val = v[4*q + r];
                    o[r] = (val*val >= THRESH && (gr0 + r) != gc) ? 1.0f : 0.0f;
                    h = h || (o[r] != 0.0f);
                }
                if (__any(h)) {
                    #pragma unroll
                    for (int r = 0; r < 4; ++r)
                        adj[(size_t)(gr0 + r) * B_SZ + gc] = o[r];
                    if (offdiag)
                        *(float4*)&adj[(size_t)gc * B_SZ + gr0] =
                            make_float4(o[0], o[1], o[2], o[3]);
                }
            }
        }
    }
}

extern "C" void kernel_launch(void* const* d_in, const int* in_sizes, int n_in,
                              void* d_out, int out_size, void* d_ws, size_t ws_size,
                              hipStream_t stream) {
    const float* x       = (const float*)d_in[0];
    const float* conv_w  = (const float*)d_in[1];
    const float* conv_b  = (const float*)d_in[2];
    const float* unitary = (const float*)d_in[3];
    const float* lin_w   = (const float*)d_in[4];
    const float* lin_b   = (const float*)d_in[5];

    float* log_probs = (float*)d_out;
    float* adj       = (float*)d_out + (size_t)B_SZ * 10;
    uchar_t* qn      = (uchar_t*)d_ws;   // 13 planes x [8192][64 B] fp8 e4m3

    preproc_kernel<<<B_SZ / 4, 256, 0, stream>>>(x, conv_w, conv_b, unitary,
                                                 lin_w, lin_b, log_probs, qn);
    gram_kernel<<<528, 512, 0, stream>>>(qn, adj);
}